// Round 1
// baseline (391.414 us; speedup 1.0000x reference)
//
#include <hip/hip_runtime.h>

#define BATCH 2
#define SEQ 2048
#define EMBED 2048
#define NHEADS 32
#define NKV 8
#define HDIM 64
#define QKV_LD 3072  // fused [Q(2048) | K(512) | V(512)] row stride
#define LOG2E 1.44269504088896f

typedef __attribute__((ext_vector_type(8))) short short8;
typedef __attribute__((ext_vector_type(4))) float f32x4;

__device__ inline float hw_exp2(float x) { return __builtin_amdgcn_exp2f(x); }

__device__ inline ushort f2bf(float f) {
  union { float f; unsigned u; } v{f};
  unsigned r = v.u + 0x7FFF + ((v.u >> 16) & 1);
  return (ushort)(r >> 16);
}
__device__ inline float bf2f(ushort u) {
  union { unsigned u; float f; } v{((unsigned)u) << 16};
  return v.f;
}
__device__ inline unsigned fbits(float f) {
  union { float f; unsigned u; } v{f};
  return v.u;
}

__device__ inline void gload16(const ushort* g, ushort* l) {
  __builtin_amdgcn_global_load_lds(
      (const __attribute__((address_space(1))) unsigned*)g,
      (__attribute__((address_space(3))) unsigned*)l, 16, 0, 0);
}

// ---------------- fused fp32 -> bf16 convert (all 5 tensors, 1 launch) ----------------
// element ranges: x[0,8388608) wq[..12582912) wk[..13631488) wv[..14680064) wo[..18874368)
__global__ __launch_bounds__(256) void cvt_all(const float* __restrict__ x,
                                               const float* __restrict__ wq,
                                               const float* __restrict__ wk,
                                               const float* __restrict__ wv,
                                               const float* __restrict__ wo,
                                               ushort* __restrict__ xb,
                                               ushort* __restrict__ wqkv,
                                               ushort* __restrict__ wob) {
  size_t e = (size_t)(blockIdx.x * blockDim.x + threadIdx.x) * 8;
  const float* src;
  ushort* dst;
  if (e < 8388608u) { src = x + e; dst = xb + e; }
  else if (e < 12582912u) { size_t o = e - 8388608u; src = wq + o; dst = wqkv + o; }
  else if (e < 13631488u) { size_t o = e - 12582912u; src = wk + o; dst = wqkv + 4194304u + o; }
  else if (e < 14680064u) { size_t o = e - 13631488u; src = wv + o; dst = wqkv + 5242880u + o; }
  else { size_t o = e - 14680064u; src = wo + o; dst = wob + o; }
  float4 v0 = ((const float4*)src)[0];
  float4 v1 = ((const float4*)src)[1];
  union { uint4 v; ushort u[8]; } pk;
  pk.u[0] = f2bf(v0.x); pk.u[1] = f2bf(v0.y); pk.u[2] = f2bf(v0.z); pk.u[3] = f2bf(v0.w);
  pk.u[4] = f2bf(v1.x); pk.u[5] = f2bf(v1.y); pk.u[6] = f2bf(v1.z); pk.u[7] = f2bf(v1.w);
  *(uint4*)dst = pk.v;
}

// ---------------- bf16 MFMA GEMM (m97 structure): C[M,N] = A * B^T ----------------
template <typename OutT>
__global__ __launch_bounds__(256) void gemm_bf16(const ushort* __restrict__ A,
                                                 const ushort* __restrict__ B,
                                                 OutT* __restrict__ C,
                                                 int M, int N, int K) {
  __shared__ ushort As[128][32];
  __shared__ ushort Bs[128][32];
  const int tid = threadIdx.x;
  const int lane = tid & 63, wave = tid >> 6;
  const int quad = lane >> 4, l16 = lane & 15;
  const int m0 = blockIdx.y * 128, n0 = blockIdx.x * 128;
  const int wm = (wave >> 1) * 64, wn = (wave & 1) * 64;
  const int srow = lane >> 2, skq = (lane & 3) * 8;

  f32x4 acc[4][4] = {};
  for (int k0 = 0; k0 < K; k0 += 32) {
    const ushort* ga = A + (size_t)(m0 + wave * 32 + srow) * K + k0 + skq;
    const ushort* gb = B + (size_t)(n0 + wave * 32 + srow) * K + k0 + skq;
    __syncthreads();
    gload16(ga, &As[wave * 32][0]);
    gload16(ga + (size_t)16 * K, &As[wave * 32 + 16][0]);
    gload16(gb, &Bs[wave * 32][0]);
    gload16(gb + (size_t)16 * K, &Bs[wave * 32 + 16][0]);
    __syncthreads();
    short8 af[4], bf[4];
#pragma unroll
    for (int i = 0; i < 4; i++) af[i] = *(short8*)&As[wm + i * 16 + l16][quad * 8];
#pragma unroll
    for (int j = 0; j < 4; j++) bf[j] = *(short8*)&Bs[wn + j * 16 + l16][quad * 8];
#pragma unroll
    for (int i = 0; i < 4; i++)
#pragma unroll
      for (int j = 0; j < 4; j++)
        acc[i][j] = __builtin_amdgcn_mfma_f32_16x16x32_bf16(af[i], bf[j], acc[i][j], 0, 0, 0);
  }
#pragma unroll
  for (int i = 0; i < 4; i++) {
#pragma unroll
    for (int r = 0; r < 4; r++) {
      size_t rg = (size_t)(m0 + wm + i * 16 + quad * 4 + r);
#pragma unroll
      for (int j = 0; j < 4; j++) {
        float v = acc[i][j][r];
        int cg = n0 + wn + j * 16 + l16;
        if constexpr (sizeof(OutT) == 2)
          C[rg * N + cg] = f2bf(v);
        else
          C[rg * N + cg] = v;
      }
    }
  }
}

// ---------------- vectorized RoPE on fused QKV ----------------
// Q heads prescaled by 0.125*log2(e) (exp2-domain softmax downstream).
// thread = (tok, hh<40, g<4): handles dims [g*8, g*8+8) and [g*8+32, g*8+40).
__global__ __launch_bounds__(256) void rope_qk(ushort* __restrict__ t,
                                               const float* __restrict__ fc,
                                               const float* __restrict__ fs,
                                               int total) {
  int idx = blockIdx.x * blockDim.x + threadIdx.x;
  if (idx >= total) return;
  int g = idx & 3;
  int hh = (idx >> 2) % 40;
  int tok = idx / 160;
  int s = tok & (SEQ - 1);
  float scale = (hh < 32) ? 0.125f * LOG2E : 1.0f;
  ushort* p = t + (size_t)tok * QKV_LD + hh * 64 + g * 8;
  union { uint4 v; ushort u[8]; } lo, hi, olo, ohi;
  lo.v = *(const uint4*)p;
  hi.v = *(const uint4*)(p + 32);
  const float* fcb = fc + s * HDIM + g * 8;
  const float* fsb = fs + s * HDIM + g * 8;
  float4 c0a = ((const float4*)fcb)[0], c0b = ((const float4*)fcb)[1];
  float4 s0a = ((const float4*)fsb)[0], s0b = ((const float4*)fsb)[1];
  float4 c1a = ((const float4*)(fcb + 32))[0], c1b = ((const float4*)(fcb + 32))[1];
  float4 s1a = ((const float4*)(fsb + 32))[0], s1b = ((const float4*)(fsb + 32))[1];
  float cc0[8] = {c0a.x, c0a.y, c0a.z, c0a.w, c0b.x, c0b.y, c0b.z, c0b.w};
  float ss0[8] = {s0a.x, s0a.y, s0a.z, s0a.w, s0b.x, s0b.y, s0b.z, s0b.w};
  float cc1[8] = {c1a.x, c1a.y, c1a.z, c1a.w, c1b.x, c1b.y, c1b.z, c1b.w};
  float ss1[8] = {s1a.x, s1a.y, s1a.z, s1a.w, s1b.x, s1b.y, s1b.z, s1b.w};
#pragma unroll
  for (int j = 0; j < 8; j++) {
    float x0 = bf2f(lo.u[j]), x1 = bf2f(hi.u[j]);
    olo.u[j] = f2bf((x0 * cc0[j] - x1 * ss0[j]) * scale);
    ohi.u[j] = f2bf((x1 * cc1[j] + x0 * ss1[j]) * scale);
  }
  *(uint4*)p = olo.v;
  *(uint4*)(p + 32) = ohi.v;
}

// ---------------- MFMA flash attention v2 ----------------
// Changes vs v1:
//  - K LDS staging removed: kf fragments loaded directly from global (L2-resident),
//    issued BEFORE the barrier so latency hides under the barrier wait.
//  - Vt double-buffered; ONE raw s_barrier per tile (manual lgkmcnt(0) drain only,
//    no vmcnt drain -> V prefetch for t+1 stays in flight across the barrier, T14).
//  - kf/vf shared across both q-tiles (u=0,1): QK and PV fused over u.
//  - T13 defer-max (THR=8 in exp2 domain), T5 setprio around MFMA clusters.
__global__ __launch_bounds__(256) void attn_mfma(const ushort* __restrict__ QKV,
                                                 ushort* __restrict__ O) {
  __shared__ ushort Vt[2][64][72];     // double-buffered [d][key]
  __shared__ ushort Pw[4][2][16][72];  // per-wave, per-u P[q][key]
  const int tid = threadIdx.x;
  const int lane = tid & 63, wave = tid >> 6;
  const int quad = lane >> 4, l16 = lane & 15;
  const int bh = blockIdx.y;
  const int b = bh >> 5, h = bh & 31, kh = h >> 2;
  const int p = blockIdx.x;
  const int qt0 = p, qt1 = 31 - p;  // work-paired q-tiles
  const int ntiles = 32 - p;

  short8 qf0[2], qf1[2];
#pragma unroll
  for (int c = 0; c < 2; c++) {
    qf0[c] = *(const short8*)(QKV +
        (size_t)(b * SEQ + qt0 * 64 + wave * 16 + l16) * QKV_LD +
        h * HDIM + c * 32 + quad * 8);
    qf1[c] = *(const short8*)(QKV +
        (size_t)(b * SEQ + qt1 * 64 + wave * 16 + l16) * QKV_LD +
        h * HDIM + c * 32 + quad * 8);
  }

  f32x4 o0[4] = {}, o1[4] = {};
  float m0 = -INFINITY, m1 = -INFINITY, l0 = 0.f, l1 = 0.f;

  const ushort* Kbase = QKV + (size_t)b * SEQ * QKV_LD + 2048 + kh * HDIM;
  const ushort* Vbase = Kbase + 512;
  const int kp = tid & 31, dg = tid >> 5;
  const int relrow = wave * 16 + l16;

  // prologue: V regs for tile 0
  uint4 va = *(const uint4*)(Vbase + (size_t)(2 * kp) * QKV_LD + dg * 8);
  uint4 vb = *(const uint4*)(Vbase + (size_t)(2 * kp + 1) * QKV_LD + dg * 8);

  for (int t = 0; t < ntiles; t++) {
    const int k0 = t * 64;
    const int cur = t & 1;
    const bool act0 = (t <= qt0);

    // prefetch V tile t+1 (clamped; stays in flight across the raw barrier)
    const int tb = (t + 1 < ntiles ? t + 1 : t) * 64;
    uint4 na = *(const uint4*)(Vbase + (size_t)(tb + 2 * kp) * QKV_LD + dg * 8);
    uint4 nb = *(const uint4*)(Vbase + (size_t)(tb + 2 * kp + 1) * QKV_LD + dg * 8);

    // stage V tile t from regs into LDS (transposed, bf16-packed)
    {
      const unsigned* vaw = (const unsigned*)&va;
      const unsigned* vbw = (const unsigned*)&vb;
#pragma unroll
      for (int j = 0; j < 8; j++) {
        unsigned pk = (j & 1)
            ? __builtin_amdgcn_perm(vbw[j >> 1], vaw[j >> 1], 0x07060302)
            : __builtin_amdgcn_perm(vbw[j >> 1], vaw[j >> 1], 0x05040100);
        *(unsigned*)&Vt[cur][dg * 8 + j][2 * kp] = pk;
      }
    }

    // K fragments direct from global (L2 hit); issued before the barrier
    short8 kf0[4], kf1[4];
#pragma unroll
    for (int nt = 0; nt < 4; nt++) {
      const ushort* kr = Kbase + (size_t)(k0 + nt * 16 + l16) * QKV_LD + quad * 8;
      kf0[nt] = *(const short8*)kr;
      kf1[nt] = *(const short8*)(kr + 32);
    }

    // drain only LDS writes, then raw barrier (no vmcnt drain)
    asm volatile("s_waitcnt lgkmcnt(0)" ::: "memory");
    __builtin_amdgcn_s_barrier();
    __builtin_amdgcn_sched_barrier(0);

    // QK^T for both q-tiles sharing kf
    f32x4 s0[4], s1[4];
    __builtin_amdgcn_s_setprio(1);
#pragma unroll
    for (int nt = 0; nt < 4; nt++) {
      f32x4 z = {};
      z = __builtin_amdgcn_mfma_f32_16x16x32_bf16(kf0[nt], qf1[0], z, 0, 0, 0);
      s1[nt] = __builtin_amdgcn_mfma_f32_16x16x32_bf16(kf1[nt], qf1[1], z, 0, 0, 0);
    }
    if (act0) {
#pragma unroll
      for (int nt = 0; nt < 4; nt++) {
        f32x4 z = {};
        z = __builtin_amdgcn_mfma_f32_16x16x32_bf16(kf0[nt], qf0[0], z, 0, 0, 0);
        s0[nt] = __builtin_amdgcn_mfma_f32_16x16x32_bf16(kf1[nt], qf0[1], z, 0, 0, 0);
      }
    }
    __builtin_amdgcn_s_setprio(0);

    // causal mask on diagonal tiles
    if (t == qt1) {
#pragma unroll
      for (int nt = 0; nt < 4; nt++)
#pragma unroll
        for (int r = 0; r < 4; r++)
          if (nt * 16 + quad * 4 + r > relrow) s1[nt][r] = -INFINITY;
    }
    if (act0 && t == qt0) {
#pragma unroll
      for (int nt = 0; nt < 4; nt++)
#pragma unroll
        for (int r = 0; r < 4; r++)
          if (nt * 16 + quad * 4 + r > relrow) s0[nt][r] = -INFINITY;
    }

    // online softmax with defer-max (T13, THR=8 in exp2 domain)
    auto smx = [&](f32x4 (&s)[4], float& mm, float& ll, f32x4 (&oo)[4], ushort* pwb) {
      float mx = s[0][0];
#pragma unroll
      for (int nt = 0; nt < 4; nt++)
#pragma unroll
        for (int r = 0; r < 4; r++) mx = fmaxf(mx, s[nt][r]);
      mx = fmaxf(mx, __shfl_xor(mx, 16));
      mx = fmaxf(mx, __shfl_xor(mx, 32));
      if (!__all(mx <= mm + 8.f)) {
        float mnew = fmaxf(mm, mx);
        float al = hw_exp2(mm - mnew);
        mm = mnew;
        ll *= al;
#pragma unroll
        for (int dt = 0; dt < 4; dt++)
#pragma unroll
          for (int r = 0; r < 4; r++) oo[dt][r] *= al;
      }
      float psum = 0.f;
#pragma unroll
      for (int nt = 0; nt < 4; nt++) {
        float p0 = hw_exp2(s[nt][0] - mm), p1 = hw_exp2(s[nt][1] - mm);
        float p2 = hw_exp2(s[nt][2] - mm), p3 = hw_exp2(s[nt][3] - mm);
        psum += (p0 + p1) + (p2 + p3);
        unsigned lo = __builtin_amdgcn_perm(fbits(p1), fbits(p0), 0x07060302);
        unsigned hi = __builtin_amdgcn_perm(fbits(p3), fbits(p2), 0x07060302);
        uint2 pk; pk.x = lo; pk.y = hi;
        *(uint2*)(pwb + l16 * 72 + nt * 16 + quad * 4) = pk;
      }
      psum += __shfl_xor(psum, 16);
      psum += __shfl_xor(psum, 32);
      ll += psum;
    };
    smx(s1, m1, l1, o1, &Pw[wave][1][0][0]);
    if (act0) smx(s0, m0, l0, o0, &Pw[wave][0][0][0]);

    // P fragments (per-wave LDS, lgkm-ordered)
    const ushort* pb1 = &Pw[wave][1][0][0] + l16 * 72;
    short8 pf1a = *(const short8*)(pb1 + quad * 8);
    short8 pf1b = *(const short8*)(pb1 + 32 + quad * 8);
    short8 pf0a = pf1a, pf0b = pf1b;
    if (act0) {
      const ushort* pb0 = &Pw[wave][0][0][0] + l16 * 72;
      pf0a = *(const short8*)(pb0 + quad * 8);
      pf0b = *(const short8*)(pb0 + 32 + quad * 8);
    }

    // PV for both q-tiles sharing vf
    __builtin_amdgcn_s_setprio(1);
#pragma unroll
    for (int dt = 0; dt < 4; dt++) {
      short8 vf0 = *(const short8*)&Vt[cur][dt * 16 + l16][quad * 8];
      short8 vf1 = *(const short8*)&Vt[cur][dt * 16 + l16][32 + quad * 8];
      o1[dt] = __builtin_amdgcn_mfma_f32_16x16x32_bf16(vf0, pf1a, o1[dt], 0, 0, 0);
      o1[dt] = __builtin_amdgcn_mfma_f32_16x16x32_bf16(vf1, pf1b, o1[dt], 0, 0, 0);
      if (act0) {
        o0[dt] = __builtin_amdgcn_mfma_f32_16x16x32_bf16(vf0, pf0a, o0[dt], 0, 0, 0);
        o0[dt] = __builtin_amdgcn_mfma_f32_16x16x32_bf16(vf1, pf0b, o0[dt], 0, 0, 0);
      }
    }
    __builtin_amdgcn_s_setprio(0);

    va = na; vb = nb;
  }

  // epilogue: both q-tiles
  {
    float inv = 1.0f / l1;
    size_t rowg = (size_t)(b * SEQ + qt1 * 64 + wave * 16 + l16) * EMBED + h * HDIM;
#pragma unroll
    for (int dt = 0; dt < 4; dt++) {
      ushort q0 = f2bf(o1[dt][0] * inv), q1 = f2bf(o1[dt][1] * inv);
      ushort q2 = f2bf(o1[dt][2] * inv), q3 = f2bf(o1[dt][3] * inv);
      uint2 pk;
      pk.x = (unsigned)q0 | ((unsigned)q1 << 16);
      pk.y = (unsigned)q2 | ((unsigned)q3 << 16);
      *(uint2*)&O[rowg + dt * 16 + quad * 4] = pk;
    }
  }
  {
    float inv = 1.0f / l0;
    size_t rowg = (size_t)(b * SEQ + qt0 * 64 + wave * 16 + l16) * EMBED + h * HDIM;
#pragma unroll
    for (int dt = 0; dt < 4; dt++) {
      ushort q0 = f2bf(o0[dt][0] * inv), q1 = f2bf(o0[dt][1] * inv);
      ushort q2 = f2bf(o0[dt][2] * inv), q3 = f2bf(o0[dt][3] * inv);
      uint2 pk;
      pk.x = (unsigned)q0 | ((unsigned)q1 << 16);
      pk.y = (unsigned)q2 | ((unsigned)q3 << 16);
      *(uint2*)&O[rowg + dt * 16 + quad * 4] = pk;
    }
  }
}

// ---------------- launch ----------------
extern "C" void kernel_launch(void* const* d_in, const int* in_sizes, int n_in,
                              void* d_out, int out_size, void* d_ws, size_t ws_size,
                              hipStream_t stream) {
  const float* x = (const float*)d_in[0];
  const float* fcos = (const float*)d_in[1];
  const float* fsin = (const float*)d_in[2];
  const float* wq = (const float*)d_in[3];
  const float* wk = (const float*)d_in[4];
  const float* wv = (const float*)d_in[5];
  const float* wo = (const float*)d_in[6];
  float* out = (float*)d_out;

  const int M = BATCH * SEQ;  // 4096
  ushort* ws = (ushort*)d_ws;
  ushort* xb = ws;
  ushort* wqkv = xb + (size_t)M * EMBED;
  ushort* wob = wqkv + (size_t)QKV_LD * EMBED;
  ushort* QKVb = wob + (size_t)EMBED * EMBED;
  ushort* Ab = QKVb + (size_t)M * QKV_LD;

  dim3 blk(256);
  // all conversions in one launch: 18874368 elems / 8 per thread / 256
  cvt_all<<<9216, blk, 0, stream>>>(x, wq, wk, wv, wo, xb, wqkv, wob);

  gemm_bf16<ushort><<<dim3(QKV_LD / 128, M / 128), blk, 0, stream>>>(xb, wqkv, QKVb, M, QKV_LD, EMBED);

  {
    int tot = M * 40 * 4;  // 655360 threads, 16 dims per thread
    rope_qk<<<(tot + 255) / 256, blk, 0, stream>>>(QKVb, fcos, fsin, tot);
  }

  attn_mfma<<<dim3(16, BATCH * NHEADS), blk, 0, stream>>>(QKVb, Ab);

  gemm_bf16<float><<<dim3(EMBED / 128, M / 128), blk, 0, stream>>>(Ab, wob, out, M, EMBED, EMBED);
}

// Round 2
// 346.013 us; speedup vs baseline: 1.1312x; 1.1312x over previous
//
#include <hip/hip_runtime.h>

#define BATCH 2
#define SEQ 2048
#define EMBED 2048
#define NHEADS 32
#define NKV 8
#define HDIM 64
#define QKV_LD 3072  // fused [Q(2048) | K(512) | V(512)] row stride
#define LOG2E 1.44269504088896f

typedef __attribute__((ext_vector_type(8))) short short8;
typedef __attribute__((ext_vector_type(4))) float f32x4;

__device__ inline float hw_exp2(float x) { return __builtin_amdgcn_exp2f(x); }

__device__ inline ushort f2bf(float f) {
  union { float f; unsigned u; } v{f};
  unsigned r = v.u + 0x7FFF + ((v.u >> 16) & 1);
  return (ushort)(r >> 16);
}
__device__ inline float bf2f(ushort u) {
  union { unsigned u; float f; } v{((unsigned)u) << 16};
  return v.f;
}
__device__ inline unsigned fbits(float f) {
  union { float f; unsigned u; } v{f};
  return v.u;
}

__device__ inline void gload16(const ushort* g, ushort* l) {
  __builtin_amdgcn_global_load_lds(
      (const __attribute__((address_space(1))) unsigned*)g,
      (__attribute__((address_space(3))) unsigned*)l, 16, 0, 0);
}

// ---------------- fused fp32 -> bf16 convert (all 5 tensors, 1 launch) ----------------
// element ranges: x[0,8388608) wq[..12582912) wk[..13631488) wv[..14680064) wo[..18874368)
__global__ __launch_bounds__(256) void cvt_all(const float* __restrict__ x,
                                               const float* __restrict__ wq,
                                               const float* __restrict__ wk,
                                               const float* __restrict__ wv,
                                               const float* __restrict__ wo,
                                               ushort* __restrict__ xb,
                                               ushort* __restrict__ wqkv,
                                               ushort* __restrict__ wob) {
  size_t e = (size_t)(blockIdx.x * blockDim.x + threadIdx.x) * 8;
  const float* src;
  ushort* dst;
  if (e < 8388608u) { src = x + e; dst = xb + e; }
  else if (e < 12582912u) { size_t o = e - 8388608u; src = wq + o; dst = wqkv + o; }
  else if (e < 13631488u) { size_t o = e - 12582912u; src = wk + o; dst = wqkv + 4194304u + o; }
  else if (e < 14680064u) { size_t o = e - 13631488u; src = wv + o; dst = wqkv + 5242880u + o; }
  else { size_t o = e - 14680064u; src = wo + o; dst = wob + o; }
  float4 v0 = ((const float4*)src)[0];
  float4 v1 = ((const float4*)src)[1];
  union { uint4 v; ushort u[8]; } pk;
  pk.u[0] = f2bf(v0.x); pk.u[1] = f2bf(v0.y); pk.u[2] = f2bf(v0.z); pk.u[3] = f2bf(v0.w);
  pk.u[4] = f2bf(v1.x); pk.u[5] = f2bf(v1.y); pk.u[6] = f2bf(v1.z); pk.u[7] = f2bf(v1.w);
  *(uint4*)dst = pk.v;
}

// ---------------- bf16 MFMA GEMM (m97 structure): C[M,N] = A * B^T ----------------
template <typename OutT>
__global__ __launch_bounds__(256) void gemm_bf16(const ushort* __restrict__ A,
                                                 const ushort* __restrict__ B,
                                                 OutT* __restrict__ C,
                                                 int M, int N, int K) {
  __shared__ ushort As[128][32];
  __shared__ ushort Bs[128][32];
  const int tid = threadIdx.x;
  const int lane = tid & 63, wave = tid >> 6;
  const int quad = lane >> 4, l16 = lane & 15;
  const int m0 = blockIdx.y * 128, n0 = blockIdx.x * 128;
  const int wm = (wave >> 1) * 64, wn = (wave & 1) * 64;
  const int srow = lane >> 2, skq = (lane & 3) * 8;

  f32x4 acc[4][4] = {};
  for (int k0 = 0; k0 < K; k0 += 32) {
    const ushort* ga = A + (size_t)(m0 + wave * 32 + srow) * K + k0 + skq;
    const ushort* gb = B + (size_t)(n0 + wave * 32 + srow) * K + k0 + skq;
    __syncthreads();
    gload16(ga, &As[wave * 32][0]);
    gload16(ga + (size_t)16 * K, &As[wave * 32 + 16][0]);
    gload16(gb, &Bs[wave * 32][0]);
    gload16(gb + (size_t)16 * K, &Bs[wave * 32 + 16][0]);
    __syncthreads();
    short8 af[4], bf[4];
#pragma unroll
    for (int i = 0; i < 4; i++) af[i] = *(short8*)&As[wm + i * 16 + l16][quad * 8];
#pragma unroll
    for (int j = 0; j < 4; j++) bf[j] = *(short8*)&Bs[wn + j * 16 + l16][quad * 8];
#pragma unroll
    for (int i = 0; i < 4; i++)
#pragma unroll
      for (int j = 0; j < 4; j++)
        acc[i][j] = __builtin_amdgcn_mfma_f32_16x16x32_bf16(af[i], bf[j], acc[i][j], 0, 0, 0);
  }
#pragma unroll
  for (int i = 0; i < 4; i++) {
#pragma unroll
    for (int r = 0; r < 4; r++) {
      size_t rg = (size_t)(m0 + wm + i * 16 + quad * 4 + r);
#pragma unroll
      for (int j = 0; j < 4; j++) {
        float v = acc[i][j][r];
        int cg = n0 + wn + j * 16 + l16;
        if constexpr (sizeof(OutT) == 2)
          C[rg * N + cg] = f2bf(v);
        else
          C[rg * N + cg] = v;
      }
    }
  }
}

// ---------------- vectorized RoPE on fused QKV ----------------
// Q heads prescaled by 0.125*log2(e) (exp2-domain softmax downstream).
// thread = (tok, hh<40, g<4): handles dims [g*8, g*8+8) and [g*8+32, g*8+40).
__global__ __launch_bounds__(256) void rope_qk(ushort* __restrict__ t,
                                               const float* __restrict__ fc,
                                               const float* __restrict__ fs,
                                               int total) {
  int idx = blockIdx.x * blockDim.x + threadIdx.x;
  if (idx >= total) return;
  int g = idx & 3;
  int hh = (idx >> 2) % 40;
  int tok = idx / 160;
  int s = tok & (SEQ - 1);
  float scale = (hh < 32) ? 0.125f * LOG2E : 1.0f;
  ushort* p = t + (size_t)tok * QKV_LD + hh * 64 + g * 8;
  union { uint4 v; ushort u[8]; } lo, hi, olo, ohi;
  lo.v = *(const uint4*)p;
  hi.v = *(const uint4*)(p + 32);
  const float* fcb = fc + s * HDIM + g * 8;
  const float* fsb = fs + s * HDIM + g * 8;
  float4 c0a = ((const float4*)fcb)[0], c0b = ((const float4*)fcb)[1];
  float4 s0a = ((const float4*)fsb)[0], s0b = ((const float4*)fsb)[1];
  float4 c1a = ((const float4*)(fcb + 32))[0], c1b = ((const float4*)(fcb + 32))[1];
  float4 s1a = ((const float4*)(fsb + 32))[0], s1b = ((const float4*)(fsb + 32))[1];
  float cc0[8] = {c0a.x, c0a.y, c0a.z, c0a.w, c0b.x, c0b.y, c0b.z, c0b.w};
  float ss0[8] = {s0a.x, s0a.y, s0a.z, s0a.w, s0b.x, s0b.y, s0b.z, s0b.w};
  float cc1[8] = {c1a.x, c1a.y, c1a.z, c1a.w, c1b.x, c1b.y, c1b.z, c1b.w};
  float ss1[8] = {s1a.x, s1a.y, s1a.z, s1a.w, s1b.x, s1b.y, s1b.z, s1b.w};
#pragma unroll
  for (int j = 0; j < 8; j++) {
    float x0 = bf2f(lo.u[j]), x1 = bf2f(hi.u[j]);
    olo.u[j] = f2bf((x0 * cc0[j] - x1 * ss0[j]) * scale);
    ohi.u[j] = f2bf((x1 * cc1[j] + x0 * ss1[j]) * scale);
  }
  *(uint4*)p = olo.v;
  *(uint4*)(p + 32) = ohi.v;
}

// ---------------- MFMA flash attention v3 ----------------
// v1 structure (cooperative LDS staging of K and V, shared by all 4 waves) with:
//  - Ks/Vt double-buffered; ONE raw s_barrier per tile, lgkmcnt(0) drain only
//    (V/K prefetch for t+1 stays in flight across the barrier - T14).
//  - K/V global loads for tile t+1 issued from regs right after tile t's ds_writes;
//    compiler's vmcnt wait lands at next iteration's ds_write (a full tile later).
//  - T13 defer-max (THR=8 in exp2 domain): skip o-rescale when max doesn't grow.
//  - T5 s_setprio(1) around MFMA clusters.
__global__ __launch_bounds__(256) void attn_mfma(const ushort* __restrict__ QKV,
                                                 ushort* __restrict__ O) {
  __shared__ ushort Ks[2][64][72];  // double-buffered [key][d]
  __shared__ ushort Vt[2][64][72];  // double-buffered [d][key]
  __shared__ ushort Pw[4][16][72];  // per-wave P[q][key]
  const int tid = threadIdx.x;
  const int lane = tid & 63, wave = tid >> 6;
  const int quad = lane >> 4, l16 = lane & 15;
  const int bh = blockIdx.y;
  const int b = bh >> 5, h = bh & 31, kh = h >> 2;
  const int p = blockIdx.x;
  const int qt[2] = {p, 31 - p};
  const int ntiles = 32 - p;

  short8 qf[2][2];
#pragma unroll
  for (int u = 0; u < 2; u++)
#pragma unroll
    for (int c = 0; c < 2; c++)
      qf[u][c] = *(const short8*)(QKV +
          (size_t)(b * SEQ + qt[u] * 64 + wave * 16 + l16) * QKV_LD +
          h * HDIM + c * 32 + quad * 8);

  f32x4 o[2][4] = {};
  float m[2] = {-INFINITY, -INFINITY}, l[2] = {0.f, 0.f};

  const ushort* Kbase = QKV + (size_t)b * SEQ * QKV_LD + 2048 + kh * HDIM;
  const ushort* Vbase = Kbase + 512;
  const int kp = tid & 31, dg = tid >> 5;
  const int relrow = wave * 16 + l16;

  // prologue: K/V regs for tile 0
  float4 ka, kb;
  uint4 va, vb;
  {
    const float4* kpp = (const float4*)(Kbase + (size_t)lane * QKV_LD + wave * 16);
    ka = kpp[0];
    kb = kpp[1];
    va = *(const uint4*)(Vbase + (size_t)(2 * kp) * QKV_LD + dg * 8);
    vb = *(const uint4*)(Vbase + (size_t)(2 * kp + 1) * QKV_LD + dg * 8);
  }

  for (int t = 0; t < ntiles; t++) {
    const int cur = t & 1;

    // stage tile t from regs into LDS
    *(float4*)&Ks[cur][lane][wave * 16] = ka;
    *(float4*)&Ks[cur][lane][wave * 16 + 8] = kb;
    {
      const unsigned* vaw = (const unsigned*)&va;
      const unsigned* vbw = (const unsigned*)&vb;
#pragma unroll
      for (int j = 0; j < 8; j++) {
        unsigned pk = (j & 1)
            ? __builtin_amdgcn_perm(vbw[j >> 1], vaw[j >> 1], 0x07060302)
            : __builtin_amdgcn_perm(vbw[j >> 1], vaw[j >> 1], 0x05040100);
        *(unsigned*)&Vt[cur][dg * 8 + j][2 * kp] = pk;
      }
    }

    // issue prefetch for tile t+1 (clamped); stays in flight across the barrier
    {
      const int tb = (t + 1 < ntiles ? t + 1 : t) * 64;
      const float4* kpp = (const float4*)(Kbase + (size_t)(tb + lane) * QKV_LD + wave * 16);
      ka = kpp[0];
      kb = kpp[1];
      va = *(const uint4*)(Vbase + (size_t)(tb + 2 * kp) * QKV_LD + dg * 8);
      vb = *(const uint4*)(Vbase + (size_t)(tb + 2 * kp + 1) * QKV_LD + dg * 8);
    }

    // drain only LDS writes, then raw barrier (no vmcnt drain)
    asm volatile("s_waitcnt lgkmcnt(0)" ::: "memory");
    __builtin_amdgcn_s_barrier();
    __builtin_amdgcn_sched_barrier(0);

#pragma unroll
    for (int u = 0; u < 2; u++) {
      const int diag = qt[u];
      if (t > diag) continue;

      f32x4 s[4];
      __builtin_amdgcn_s_setprio(1);
#pragma unroll
      for (int nt = 0; nt < 4; nt++) {
        short8 kf0 = *(short8*)&Ks[cur][nt * 16 + l16][quad * 8];
        short8 kf1 = *(short8*)&Ks[cur][nt * 16 + l16][32 + quad * 8];
        f32x4 z = {};
        z = __builtin_amdgcn_mfma_f32_16x16x32_bf16(kf0, qf[u][0], z, 0, 0, 0);
        s[nt] = __builtin_amdgcn_mfma_f32_16x16x32_bf16(kf1, qf[u][1], z, 0, 0, 0);
      }
      __builtin_amdgcn_s_setprio(0);

      if (t == diag) {
#pragma unroll
        for (int nt = 0; nt < 4; nt++)
#pragma unroll
          for (int r = 0; r < 4; r++)
            if (nt * 16 + quad * 4 + r > relrow) s[nt][r] = -INFINITY;
      }

      float mx = s[0][0];
#pragma unroll
      for (int nt = 0; nt < 4; nt++)
#pragma unroll
        for (int r = 0; r < 4; r++) mx = fmaxf(mx, s[nt][r]);
      mx = fmaxf(mx, __shfl_xor(mx, 16));
      mx = fmaxf(mx, __shfl_xor(mx, 32));

      // T13 defer-max: only rescale when the tile max grows past the threshold
      if (!__all(mx <= m[u] + 8.f)) {
        float mnew = fmaxf(m[u], mx);
        float al = hw_exp2(m[u] - mnew);
        m[u] = mnew;
        l[u] *= al;
#pragma unroll
        for (int dt = 0; dt < 4; dt++)
#pragma unroll
          for (int r = 0; r < 4; r++) o[u][dt][r] *= al;
      }

      float psum = 0.f;
#pragma unroll
      for (int nt = 0; nt < 4; nt++) {
        float p0 = hw_exp2(s[nt][0] - m[u]), p1 = hw_exp2(s[nt][1] - m[u]);
        float p2 = hw_exp2(s[nt][2] - m[u]), p3 = hw_exp2(s[nt][3] - m[u]);
        psum += (p0 + p1) + (p2 + p3);
        unsigned lo = __builtin_amdgcn_perm(fbits(p1), fbits(p0), 0x07060302);
        unsigned hi = __builtin_amdgcn_perm(fbits(p3), fbits(p2), 0x07060302);
        uint2 pk; pk.x = lo; pk.y = hi;
        *(uint2*)&Pw[wave][l16][nt * 16 + quad * 4] = pk;
      }
      psum += __shfl_xor(psum, 16);
      psum += __shfl_xor(psum, 32);
      l[u] += psum;

      short8 pf0 = *(short8*)&Pw[wave][l16][quad * 8];
      short8 pf1 = *(short8*)&Pw[wave][l16][32 + quad * 8];
      __builtin_amdgcn_s_setprio(1);
#pragma unroll
      for (int dt = 0; dt < 4; dt++) {
        short8 vf0 = *(short8*)&Vt[cur][dt * 16 + l16][quad * 8];
        short8 vf1 = *(short8*)&Vt[cur][dt * 16 + l16][32 + quad * 8];
        o[u][dt] = __builtin_amdgcn_mfma_f32_16x16x32_bf16(vf0, pf0, o[u][dt], 0, 0, 0);
        o[u][dt] = __builtin_amdgcn_mfma_f32_16x16x32_bf16(vf1, pf1, o[u][dt], 0, 0, 0);
      }
      __builtin_amdgcn_s_setprio(0);
    }
  }

#pragma unroll
  for (int u = 0; u < 2; u++) {
    float inv = 1.0f / l[u];
    size_t rowg = (size_t)(b * SEQ + qt[u] * 64 + wave * 16 + l16) * EMBED + h * HDIM;
#pragma unroll
    for (int dt = 0; dt < 4; dt++) {
      ushort q0 = f2bf(o[u][dt][0] * inv), q1 = f2bf(o[u][dt][1] * inv);
      ushort q2 = f2bf(o[u][dt][2] * inv), q3 = f2bf(o[u][dt][3] * inv);
      uint2 pk;
      pk.x = (unsigned)q0 | ((unsigned)q1 << 16);
      pk.y = (unsigned)q2 | ((unsigned)q3 << 16);
      *(uint2*)&O[rowg + dt * 16 + quad * 4] = pk;
    }
  }
}

// ---------------- launch ----------------
extern "C" void kernel_launch(void* const* d_in, const int* in_sizes, int n_in,
                              void* d_out, int out_size, void* d_ws, size_t ws_size,
                              hipStream_t stream) {
  const float* x = (const float*)d_in[0];
  const float* fcos = (const float*)d_in[1];
  const float* fsin = (const float*)d_in[2];
  const float* wq = (const float*)d_in[3];
  const float* wk = (const float*)d_in[4];
  const float* wv = (const float*)d_in[5];
  const float* wo = (const float*)d_in[6];
  float* out = (float*)d_out;

  const int M = BATCH * SEQ;  // 4096
  ushort* ws = (ushort*)d_ws;
  ushort* xb = ws;
  ushort* wqkv = xb + (size_t)M * EMBED;
  ushort* wob = wqkv + (size_t)QKV_LD * EMBED;
  ushort* QKVb = wob + (size_t)EMBED * EMBED;
  ushort* Ab = QKVb + (size_t)M * QKV_LD;

  dim3 blk(256);
  // all conversions in one launch: 18874368 elems / 8 per thread / 256
  cvt_all<<<9216, blk, 0, stream>>>(x, wq, wk, wv, wo, xb, wqkv, wob);

  gemm_bf16<ushort><<<dim3(QKV_LD / 128, M / 128), blk, 0, stream>>>(xb, wqkv, QKVb, M, QKV_LD, EMBED);

  {
    int tot = M * 40 * 4;  // 655360 threads, 16 dims per thread
    rope_qk<<<(tot + 255) / 256, blk, 0, stream>>>(QKVb, fcos, fsin, tot);
  }

  attn_mfma<<<dim3(16, BATCH * NHEADS), blk, 0, stream>>>(QKVb, Ab);

  gemm_bf16<float><<<dim3(EMBED / 128, M / 128), blk, 0, stream>>>(Ab, wob, out, M, EMBED, EMBED);
}